// Round 2
// baseline (274.125 us; speedup 1.0000x reference)
//
#include <hip/hip_runtime.h>

// Problem constants (match reference)
#define N_NODES 100000
#define N_EDGES 1200000
#define DIM     64
#define BGRAPHS 1000
#define NCLASS  10
#define BN_EPS  1e-5f

// CSR-build partition constants
#define NBUCK   256            // coarse buckets
#define NPB     391            // nodes per bucket (256*391 = 100096 >= N)
#define MAGIC   10984572u      // ceil(2^32/391): bucket = umulhi(d, MAGIC)
#define CHUNK   8192           // edges per partition block
#define NBLK_P  147            // ceil(E / CHUNK)
#define CAP     8192           // refine LDS staging capacity (>= max bucket edges)
#define NB_C    3125           // N*DIM/8/256 convert blocks

typedef __attribute__((ext_vector_type(8))) short   bfx8;   // 8 bf16 MFMA A/B frag
typedef __attribute__((ext_vector_type(4))) float   f32x4;  // MFMA C/D frag
typedef __attribute__((ext_vector_type(8))) unsigned short u16x8;

__device__ __forceinline__ unsigned short f2bf(float f) {
    unsigned u = __builtin_bit_cast(unsigned, f);
    unsigned r = (u + 0x7FFFu + ((u >> 16) & 1u)) >> 16;   // RNE
    return (unsigned short)r;
}
__device__ __forceinline__ float bf2f(unsigned short h) {
    unsigned u = ((unsigned)h) << 16;
    return __builtin_bit_cast(float, u);
}

// ---------------------------------------------------------------------------
// Kernel A (merged): blocks [0,NBLK_P) = per-chunk bucket histogram partials;
// blocks [NBLK_P, NBLK_P+NB_C) = fp32->bf16 convert + zero xs.
// Partials written (not atomic-accumulated) so no zero-init dependency.
// ---------------------------------------------------------------------------
__global__ __launch_bounds__(256) void convhist_kernel(
    const float* __restrict__ x, unsigned short* __restrict__ xb,
    float* __restrict__ xs, const int* __restrict__ ei,
    int* __restrict__ gpart) {
    __shared__ int cnt[NBUCK];
    int t = threadIdx.x;
    if (blockIdx.x < NBLK_P) {
        int blk = blockIdx.x;
        cnt[t] = 0;
        __syncthreads();
        int e0 = blk * CHUNK;
        for (int i = t; i < CHUNK; i += 256) {
            int e = e0 + i;
            if (e >= N_EDGES) break;
            unsigned d = (unsigned)ei[N_EDGES + e];
            atomicAdd(&cnt[__umulhi(d, MAGIC)], 1);
        }
        __syncthreads();
        gpart[blk * NBUCK + t] = cnt[t];
    } else {
        int i = (blockIdx.x - NBLK_P) * 256 + t;
        const int n8 = N_NODES * DIM / 8;
        if (i < n8) {
            float4 a = ((const float4*)x)[i * 2];
            float4 b = ((const float4*)x)[i * 2 + 1];
            u16x8 o;
            o[0] = f2bf(a.x); o[1] = f2bf(a.y); o[2] = f2bf(a.z); o[3] = f2bf(a.w);
            o[4] = f2bf(b.x); o[5] = f2bf(b.y); o[6] = f2bf(b.z); o[7] = f2bf(b.w);
            ((u16x8*)xb)[i] = o;
        }
        if (i < BGRAPHS * DIM) xs[i] = 0.f;
    }
}

// ---------------------------------------------------------------------------
// Single-block scan: reduce 147 partials per bucket, exclusive-scan 256
// totals -> base[257]; init cursor = base for part's chunk reservation.
// ---------------------------------------------------------------------------
__global__ __launch_bounds__(256) void scanB_kernel(const int* __restrict__ gpart,
                                                    int* __restrict__ base,
                                                    int* __restrict__ cursor) {
    __shared__ int tmp[256];
    int t = threadIdx.x;
    int s = 0;
    for (int blk = 0; blk < NBLK_P; ++blk) s += gpart[blk * NBUCK + t];
    tmp[t] = s;
    __syncthreads();
    for (int off = 1; off < 256; off <<= 1) {
        int a = (t >= off) ? tmp[t - off] : 0;
        __syncthreads();
        tmp[t] += a;
        __syncthreads();
    }
    int excl = tmp[t] - s;
    base[t] = excl;
    cursor[t] = excl;
    if (t == 255) base[256] = N_EDGES;
}

// ---------------------------------------------------------------------------
// Partition: per-block LDS count, reserve per-bucket chunk with ONE global
// atomicAdd per (block,bucket), then place edges. Within-bucket order is
// arbitrary -- refine counting-sorts by dst anyway.
// ---------------------------------------------------------------------------
__global__ __launch_bounds__(256) void part_kernel(const int* __restrict__ ei,
                                                   int* __restrict__ cursor,
                                                   int* __restrict__ srcbuf,
                                                   unsigned short* __restrict__ dstlbuf) {
    __shared__ int cnt[NBUCK];
    __shared__ int cur[NBUCK];
    int t = threadIdx.x, blk = blockIdx.x;
    cnt[t] = 0;
    __syncthreads();
    int e0 = blk * CHUNK;
    for (int i = t; i < CHUNK; i += 256) {
        int e = e0 + i;
        if (e >= N_EDGES) break;
        unsigned d = (unsigned)ei[N_EDGES + e];
        atomicAdd(&cnt[__umulhi(d, MAGIC)], 1);
    }
    __syncthreads();
    cur[t] = atomicAdd(&cursor[t], cnt[t]);
    __syncthreads();
    for (int i = t; i < CHUNK; i += 256) {
        int e = e0 + i;
        if (e >= N_EDGES) break;
        unsigned d = (unsigned)ei[N_EDGES + e];
        int s = ei[e];
        int b = __umulhi(d, MAGIC);
        int pos = atomicAdd(&cur[b], 1);
        srcbuf[pos] = s;
        dstlbuf[pos] = (unsigned short)(d - b * NPB);
    }
}

// ---------------------------------------------------------------------------
// Refine: one block per bucket; LDS counting sort by dst_local; coalesced
// csr_src write; emits rowptr from the local exclusive scan.
// ---------------------------------------------------------------------------
__global__ __launch_bounds__(256) void refine_kernel(const int* __restrict__ srcbuf,
                                                     const unsigned short* __restrict__ dstlbuf,
                                                     const int* __restrict__ base,
                                                     int* __restrict__ csr_src,
                                                     int* __restrict__ rowptr) {
    __shared__ int cnt[NPB + 1];
    __shared__ int cur[NPB + 1];
    __shared__ int tmp[256];
    __shared__ int outb[CAP];
    int t = threadIdx.x, b = blockIdx.x;
    int beg = base[b];
    int end = base[b + 1];

    for (int i = t; i < NPB + 1; i += 256) cnt[i] = 0;
    __syncthreads();
    for (int i = beg + t; i < end; i += 256)
        atomicAdd(&cnt[dstlbuf[i]], 1);
    __syncthreads();

    // exclusive scan over NPB entries (2 elems/thread)
    int i0 = 2 * t, i1 = 2 * t + 1;
    int v0 = (i0 < NPB) ? cnt[i0] : 0;
    int v1 = (i1 < NPB) ? cnt[i1] : 0;
    int s = v0 + v1;
    tmp[t] = s;
    __syncthreads();
    for (int off = 1; off < 256; off <<= 1) {
        int a = (t >= off) ? tmp[t - off] : 0;
        __syncthreads();
        tmp[t] += a;
        __syncthreads();
    }
    int excl = tmp[t] - s;
    if (i0 < NPB) cur[i0] = excl;
    if (i1 < NPB) cur[i1] = excl + v0;
    {
        int g0 = b * NPB + i0;
        if (i0 < NPB && g0 < N_NODES) rowptr[g0] = beg + excl;
        int g1 = b * NPB + i1;
        if (i1 < NPB && g1 < N_NODES) rowptr[g1] = beg + excl + v0;
    }
    if (b == NBUCK - 1 && t == 0) rowptr[N_NODES] = N_EDGES;
    __syncthreads();

    for (int i = beg + t; i < end; i += 256) {
        int dl = dstlbuf[i];
        int pos = atomicAdd(&cur[dl], 1);
        if (pos < CAP) outb[pos] = srcbuf[i];
    }
    __syncthreads();

    int nb = end - beg; if (nb > CAP) nb = CAP;
    for (int i = t; i < nb; i += 256) csr_src[beg + i] = outb[i];
}

// ---------------------------------------------------------------------------
// In-register GIN aggregation for one (row, q) pair: 32B slice pair of the
// aggregated row, fp32 accumulate (identical numerics to old gather kernel).
// ---------------------------------------------------------------------------
__device__ __forceinline__ void gather_row(const unsigned short* __restrict__ feat,
                                           const int* __restrict__ rowptr,
                                           const int* __restrict__ csr_src,
                                           int rowA, int q,
                                           float* accl, float* acch) {
    const u16x8* f8 = (const u16x8*)feat;
    u16x8 s0 = f8[(long long)rowA * 8 + q];
    u16x8 s1 = f8[(long long)rowA * 8 + 4 + q];
    #pragma unroll
    for (int j = 0; j < 8; ++j) { accl[j] = bf2f(s0[j]); acch[j] = bf2f(s1[j]); }
    int k = rowptr[rowA], end = rowptr[rowA + 1];
    for (; k + 2 <= end; k += 2) {
        int sa = csr_src[k], sb = csr_src[k + 1];
        u16x8 va0 = f8[(long long)sa * 8 + q];
        u16x8 va1 = f8[(long long)sa * 8 + 4 + q];
        u16x8 vb0 = f8[(long long)sb * 8 + q];
        u16x8 vb1 = f8[(long long)sb * 8 + 4 + q];
        #pragma unroll
        for (int j = 0; j < 8; ++j) {
            accl[j] += bf2f(va0[j]) + bf2f(vb0[j]);
            acch[j] += bf2f(va1[j]) + bf2f(vb1[j]);
        }
    }
    if (k < end) {
        int sa = csr_src[k];
        u16x8 va0 = f8[(long long)sa * 8 + q];
        u16x8 va1 = f8[(long long)sa * 8 + 4 + q];
        #pragma unroll
        for (int j = 0; j < 8; ++j) {
            accl[j] += bf2f(va0[j]);
            acch[j] += bf2f(va1[j]);
        }
    }
}

// ---------------------------------------------------------------------------
// B-fragment loader: element j = W[(kt*32 + q*8 + j)][col]  (fp32 W -> bf16)
// ---------------------------------------------------------------------------
__device__ __forceinline__ bfx8 load_wfrag(const float* __restrict__ W, int kt, int q, int col) {
    bfx8 f;
    #pragma unroll
    for (int j = 0; j < 8; ++j)
        f[j] = (short)f2bf(W[(kt * 32 + q * 8 + j) * 64 + col]);
    return f;
}

// ---------------------------------------------------------------------------
// Fused agg1 + conv1 MLP: h2 = relu(relu(bn1((x+scatter(x)) @ W1a + b1a)) @ W1b + b1b)
// ---------------------------------------------------------------------------
__global__ __launch_bounds__(256) void mlp1_kernel(
    const unsigned short* __restrict__ xbf,
    const int* __restrict__ rowptr, const int* __restrict__ csr_src,
    const float* __restrict__ W1a, const float* __restrict__ b1a,
    const float* __restrict__ g1,  const float* __restrict__ be1,
    const float* __restrict__ m1,  const float* __restrict__ v1,
    const float* __restrict__ W1b, const float* __restrict__ b1b,
    unsigned short* __restrict__ h2) {
    __shared__ unsigned short h1t[4][16 * 72];
    __shared__ unsigned short outt[4][16 * 64];

    int t = threadIdx.x;
    int w = t >> 6, lane = t & 63;
    int m = lane & 15, q = lane >> 4;
    int row0 = blockIdx.x * 64 + w * 16;

    bfx8 wa[4][2], wb[4][2];
    #pragma unroll
    for (int nt = 0; nt < 4; ++nt) {
        #pragma unroll
        for (int kt = 0; kt < 2; ++kt) {
            wa[nt][kt] = load_wfrag(W1a, kt, q, nt * 16 + m);
            wb[nt][kt] = load_wfrag(W1b, kt, q, nt * 16 + m);
        }
    }
    float A1[4], B1[4], B2c[4];
    #pragma unroll
    for (int nt = 0; nt < 4; ++nt) {
        int c = nt * 16 + m;
        float s = g1[c] * rsqrtf(v1[c] + BN_EPS);
        A1[nt] = s;
        B1[nt] = b1a[c] * s + (be1[c] - m1[c] * s);
        B2c[nt] = b1b[c];
    }

    int rowA = row0 + m;
    if (rowA > N_NODES - 1) rowA = N_NODES - 1;
    float accl[8], acch[8];
    gather_row(xbf, rowptr, csr_src, rowA, q, accl, acch);
    bfx8 a0, a1;
    #pragma unroll
    for (int j = 0; j < 8; ++j) {
        a0[j] = (short)f2bf(accl[j]);
        a1[j] = (short)f2bf(acch[j]);
    }

    f32x4 acc[4];
    #pragma unroll
    for (int nt = 0; nt < 4; ++nt) {
        acc[nt] = (f32x4){0.f, 0.f, 0.f, 0.f};
        acc[nt] = __builtin_amdgcn_mfma_f32_16x16x32_bf16(a0, wa[nt][0], acc[nt], 0, 0, 0);
        acc[nt] = __builtin_amdgcn_mfma_f32_16x16x32_bf16(a1, wa[nt][1], acc[nt], 0, 0, 0);
    }
    #pragma unroll
    for (int nt = 0; nt < 4; ++nt)
        #pragma unroll
        for (int r = 0; r < 4; ++r) {
            float v = fmaxf(acc[nt][r] * A1[nt] + B1[nt], 0.f);
            h1t[w][(q * 4 + r) * 72 + nt * 16 + m] = f2bf(v);
        }
    __syncthreads();

    const bfx8* hp = (const bfx8*)&h1t[w][m * 72];
    bfx8 c0 = hp[q];
    bfx8 c1 = hp[4 + q];
    f32x4 acc2[4];
    #pragma unroll
    for (int nt = 0; nt < 4; ++nt) {
        acc2[nt] = (f32x4){0.f, 0.f, 0.f, 0.f};
        acc2[nt] = __builtin_amdgcn_mfma_f32_16x16x32_bf16(c0, wb[nt][0], acc2[nt], 0, 0, 0);
        acc2[nt] = __builtin_amdgcn_mfma_f32_16x16x32_bf16(c1, wb[nt][1], acc2[nt], 0, 0, 0);
    }
    #pragma unroll
    for (int nt = 0; nt < 4; ++nt)
        #pragma unroll
        for (int r = 0; r < 4; ++r) {
            float v = fmaxf(acc2[nt][r] + B2c[nt], 0.f);
            outt[w][(q * 4 + r) * 64 + nt * 16 + m] = f2bf(v);
        }
    __syncthreads();

    #pragma unroll
    for (int i = lane; i < 128; i += 64) {
        int rr = i >> 3, cc = i & 7;
        int rg = row0 + rr;
        if (rg < N_NODES)
            ((float4*)h2)[(long long)rg * 8 + cc] = *(const float4*)&outt[w][rr * 64 + cc * 8];
    }
}

// ---------------------------------------------------------------------------
// Fused agg2 + conv2 + pool: h4 = relu(bn2((h2+scatter(h2)) @ W2 + b2));
// xs[batch[row]] += h4
// ---------------------------------------------------------------------------
__global__ __launch_bounds__(256) void mlp2_kernel(
    const unsigned short* __restrict__ h2,
    const int* __restrict__ rowptr, const int* __restrict__ csr_src,
    const float* __restrict__ W2, const float* __restrict__ b2,
    const float* __restrict__ g2, const float* __restrict__ be2,
    const float* __restrict__ m2, const float* __restrict__ v2,
    const int* __restrict__ batch,
    float* __restrict__ xs) {
    __shared__ float pool[64 * 64];
    __shared__ int bts[64];

    int t = threadIdx.x;
    int w = t >> 6, lane = t & 63;
    int m = lane & 15, q = lane >> 4;
    int row0b = blockIdx.x * 64;
    int row0 = row0b + w * 16;

    bfx8 wf[4][2];
    #pragma unroll
    for (int nt = 0; nt < 4; ++nt)
        #pragma unroll
        for (int kt = 0; kt < 2; ++kt)
            wf[nt][kt] = load_wfrag(W2, kt, q, nt * 16 + m);
    float A[4], Bc[4];
    #pragma unroll
    for (int nt = 0; nt < 4; ++nt) {
        int c = nt * 16 + m;
        float s = g2[c] * rsqrtf(v2[c] + BN_EPS);
        A[nt] = s;
        Bc[nt] = b2[c] * s + (be2[c] - m2[c] * s);
    }
    if (t < 64) {
        int rg = row0b + t;
        bts[t] = (rg < N_NODES) ? batch[rg] : -1;
    }

    int rowA = row0 + m;
    if (rowA > N_NODES - 1) rowA = N_NODES - 1;
    float accl[8], acch[8];
    gather_row(h2, rowptr, csr_src, rowA, q, accl, acch);
    bfx8 a0, a1;
    #pragma unroll
    for (int j = 0; j < 8; ++j) {
        a0[j] = (short)f2bf(accl[j]);
        a1[j] = (short)f2bf(acch[j]);
    }

    f32x4 acc[4];
    #pragma unroll
    for (int nt = 0; nt < 4; ++nt) {
        acc[nt] = (f32x4){0.f, 0.f, 0.f, 0.f};
        acc[nt] = __builtin_amdgcn_mfma_f32_16x16x32_bf16(a0, wf[nt][0], acc[nt], 0, 0, 0);
        acc[nt] = __builtin_amdgcn_mfma_f32_16x16x32_bf16(a1, wf[nt][1], acc[nt], 0, 0, 0);
    }
    #pragma unroll
    for (int nt = 0; nt < 4; ++nt)
        #pragma unroll
        for (int r = 0; r < 4; ++r) {
            float v = fmaxf(acc[nt][r] * A[nt] + Bc[nt], 0.f);
            pool[(w * 16 + q * 4 + r) * 64 + nt * 16 + m] = v;
        }
    __syncthreads();

    int col = t & 63;
    int r0 = (t >> 6) * 16;
    int cb = bts[r0];
    float cur = 0.f;
    #pragma unroll
    for (int r = 0; r < 16; ++r) {
        int b = bts[r0 + r];
        if (b != cb) {
            if (cb >= 0) unsafeAtomicAdd(&xs[cb * 64 + col], cur);
            cb = b;
            cur = 0.f;
        }
        cur += pool[(r0 + r) * 64 + col];
    }
    if (cb >= 0) unsafeAtomicAdd(&xs[cb * 64 + col], cur);
}

// ---------------------------------------------------------------------------
// Head: x_topo = relu(topo @ Wt + bt); out = [x_struct, x_topo] @ Wc + bc
// ---------------------------------------------------------------------------
__global__ __launch_bounds__(64) void head_kernel(
    const float* __restrict__ xs, const float* __restrict__ topo,
    const float* __restrict__ Wt, const float* __restrict__ bt,
    const float* __restrict__ Wc, const float* __restrict__ bc,
    float* __restrict__ out) {
    __shared__ float trow[64];
    __shared__ float comb[128];
    int b = blockIdx.x;
    int h = threadIdx.x;
    trow[h] = topo[b * 64 + h];
    __syncthreads();
    float acc = bt[h];
    #pragma unroll
    for (int k = 0; k < 64; ++k) acc += trow[k] * Wt[k * 64 + h];
    comb[h] = xs[b * 64 + h];
    comb[64 + h] = fmaxf(acc, 0.f);
    __syncthreads();
    if (h < NCLASS) {
        float o = bc[h];
        #pragma unroll
        for (int k = 0; k < 128; ++k) o += comb[k] * Wc[k * NCLASS + h];
        out[b * NCLASS + h] = o;
    }
}

// ---------------------------------------------------------------------------
extern "C" void kernel_launch(void* const* d_in, const int* in_sizes, int n_in,
                              void* d_out, int out_size, void* d_ws, size_t ws_size,
                              hipStream_t stream) {
    const float* x     = (const float*)d_in[0];
    const int*   ei    = (const int*)d_in[1];
    const int*   batch = (const int*)d_in[2];
    const float* topo  = (const float*)d_in[3];
    const float* W1a   = (const float*)d_in[4];
    const float* b1a   = (const float*)d_in[5];
    const float* g1    = (const float*)d_in[6];
    const float* be1   = (const float*)d_in[7];
    const float* m1    = (const float*)d_in[8];
    const float* v1    = (const float*)d_in[9];
    const float* W1b   = (const float*)d_in[10];
    const float* b1b   = (const float*)d_in[11];
    const float* W2    = (const float*)d_in[12];
    const float* b2    = (const float*)d_in[13];
    const float* g2    = (const float*)d_in[14];
    const float* be2   = (const float*)d_in[15];
    const float* m2    = (const float*)d_in[16];
    const float* v2    = (const float*)d_in[17];
    const float* Wt    = (const float*)d_in[18];
    const float* bt    = (const float*)d_in[19];
    const float* Wc    = (const float*)d_in[20];
    const float* bc    = (const float*)d_in[21];
    float* out = (float*)d_out;

    // Workspace layout (16B-aligned chunks)
    char* p = (char*)d_ws;
    unsigned short* xbf  = (unsigned short*)p; p += (size_t)N_NODES * DIM * 2;  // 12.8 MB
    unsigned short* bufB = (unsigned short*)p; p += (size_t)N_NODES * DIM * 2;  // 12.8 MB
    float* xs      = (float*)p; p += (size_t)BGRAPHS * DIM * 4;                 // 256 KB
    int*   rowptr  = (int*)p;   p += (size_t)(N_NODES + 16) * 4;                // 400 KB
    int*   gpart   = (int*)p;   p += (size_t)NBLK_P * NBUCK * 4;                // 150 KB
    int*   base    = (int*)p;   p += 1040;                                      // 257 ints (1028 B, 16B-aligned slot)
    int*   cursor  = (int*)p;   p += 1024;                                      // 256 ints
    int*   srcbuf  = (int*)p;   p += (size_t)N_EDGES * 4;                       // 4.8 MB
    unsigned short* dstlbuf = (unsigned short*)p; p += (size_t)N_EDGES * 2;     // 2.4 MB
    int*   csr_src = (int*)p;                                                   // 4.8 MB

    // 1) convert + per-chunk bucket histogram (independent work, one launch)
    convhist_kernel<<<NBLK_P + NB_C, 256, 0, stream>>>(x, xbf, xs, ei, gpart);
    // 2) bucket totals -> exclusive scan -> base/cursor
    scanB_kernel<<<1, 256, 0, stream>>>(gpart, base, cursor);
    // 3) partition edges into bucket regions (chunk reservation, arbitrary order)
    part_kernel<<<NBLK_P, 256, 0, stream>>>(ei, cursor, srcbuf, dstlbuf);
    // 4) per-bucket counting sort -> csr_src + rowptr
    refine_kernel<<<NBUCK, 256, 0, stream>>>(srcbuf, dstlbuf, base, csr_src, rowptr);
    // 5) fused agg1 + conv1 MLP (MFMA): bufB = h2 (bf16)
    mlp1_kernel<<<(N_NODES + 63) / 64, 256, 0, stream>>>(
        xbf, rowptr, csr_src, W1a, b1a, g1, be1, m1, v1, W1b, b1b, bufB);
    // 6) fused agg2 + conv2 + pool (MFMA)
    mlp2_kernel<<<(N_NODES + 63) / 64, 256, 0, stream>>>(
        bufB, rowptr, csr_src, W2, b2, g2, be2, m2, v2, batch, xs);
    // 7) head
    head_kernel<<<BGRAPHS, 64, 0, stream>>>(xs, topo, Wt, bt, Wc, bc, out);
}

// Round 3
// 252.940 us; speedup vs baseline: 1.0838x; 1.0838x over previous
//
#include <hip/hip_runtime.h>

// Problem constants (match reference)
#define N_NODES 100000
#define N_EDGES 1200000
#define DIM     64
#define BGRAPHS 1000
#define NCLASS  10
#define BN_EPS  1e-5f

// CSR-build partition constants
#define NBUCK   256            // coarse buckets
#define NPB     391            // nodes per bucket (256*391 = 100096 >= N)
#define MAGIC   10984572u      // ceil(2^32/391): bucket = umulhi(d, MAGIC)
#define CHUNK   8192           // edges per partition block
#define NBLK_P  147            // ceil(E / CHUNK)
#define CAP     8192           // refine LDS staging capacity (>= max bucket edges)
#define NB_C    3125           // N*DIM/8/256 convert blocks

typedef __attribute__((ext_vector_type(8))) short   bfx8;   // 8 bf16 MFMA A/B frag
typedef __attribute__((ext_vector_type(4))) float   f32x4;  // MFMA C/D frag
typedef __attribute__((ext_vector_type(8))) unsigned short u16x8;

__device__ __forceinline__ unsigned short f2bf(float f) {
    unsigned u = __builtin_bit_cast(unsigned, f);
    unsigned r = (u + 0x7FFFu + ((u >> 16) & 1u)) >> 16;   // RNE
    return (unsigned short)r;
}
__device__ __forceinline__ float bf2f(unsigned short h) {
    unsigned u = ((unsigned)h) << 16;
    return __builtin_bit_cast(float, u);
}

// ---------------------------------------------------------------------------
// Kernel A (merged): blocks [0,NBLK_P) = per-chunk bucket histogram partials;
// blocks [NBLK_P, NBLK_P+NB_C) = fp32->bf16 convert + zero xs.
// ---------------------------------------------------------------------------
__global__ __launch_bounds__(256) void convhist_kernel(
    const float* __restrict__ x, unsigned short* __restrict__ xb,
    float* __restrict__ xs, const int* __restrict__ ei,
    int* __restrict__ gpart) {
    __shared__ int cnt[NBUCK];
    int t = threadIdx.x;
    if (blockIdx.x < NBLK_P) {
        int blk = blockIdx.x;
        cnt[t] = 0;
        __syncthreads();
        int e0 = blk * CHUNK;
        for (int i = t; i < CHUNK; i += 256) {
            int e = e0 + i;
            if (e >= N_EDGES) break;
            unsigned d = (unsigned)ei[N_EDGES + e];
            atomicAdd(&cnt[__umulhi(d, MAGIC)], 1);
        }
        __syncthreads();
        gpart[blk * NBUCK + t] = cnt[t];
    } else {
        int i = (blockIdx.x - NBLK_P) * 256 + t;
        const int n8 = N_NODES * DIM / 8;
        if (i < n8) {
            float4 a = ((const float4*)x)[i * 2];
            float4 b = ((const float4*)x)[i * 2 + 1];
            u16x8 o;
            o[0] = f2bf(a.x); o[1] = f2bf(a.y); o[2] = f2bf(a.z); o[3] = f2bf(a.w);
            o[4] = f2bf(b.x); o[5] = f2bf(b.y); o[6] = f2bf(b.z); o[7] = f2bf(b.w);
            ((u16x8*)xb)[i] = o;
        }
        if (i < BGRAPHS * DIM) xs[i] = 0.f;
    }
}

// ---------------------------------------------------------------------------
// Single-block scan: reduce 147 partials per bucket, exclusive-scan 256
// totals -> base[257]; init cursor = base for part's chunk reservation.
// ---------------------------------------------------------------------------
__global__ __launch_bounds__(256) void scanB_kernel(const int* __restrict__ gpart,
                                                    int* __restrict__ base,
                                                    int* __restrict__ cursor) {
    __shared__ int tmp[256];
    int t = threadIdx.x;
    int s = 0;
    for (int blk = 0; blk < NBLK_P; ++blk) s += gpart[blk * NBUCK + t];
    tmp[t] = s;
    __syncthreads();
    for (int off = 1; off < 256; off <<= 1) {
        int a = (t >= off) ? tmp[t - off] : 0;
        __syncthreads();
        tmp[t] += a;
        __syncthreads();
    }
    int excl = tmp[t] - s;
    base[t] = excl;
    cursor[t] = excl;
    if (t == 255) base[256] = N_EDGES;
}

// ---------------------------------------------------------------------------
// Partition: per-block LDS count, reserve per-bucket chunk with ONE global
// atomicAdd per (block,bucket), then place edges.
// ---------------------------------------------------------------------------
__global__ __launch_bounds__(256) void part_kernel(const int* __restrict__ ei,
                                                   int* __restrict__ cursor,
                                                   int* __restrict__ srcbuf,
                                                   unsigned short* __restrict__ dstlbuf) {
    __shared__ int cnt[NBUCK];
    __shared__ int cur[NBUCK];
    int t = threadIdx.x, blk = blockIdx.x;
    cnt[t] = 0;
    __syncthreads();
    int e0 = blk * CHUNK;
    for (int i = t; i < CHUNK; i += 256) {
        int e = e0 + i;
        if (e >= N_EDGES) break;
        unsigned d = (unsigned)ei[N_EDGES + e];
        atomicAdd(&cnt[__umulhi(d, MAGIC)], 1);
    }
    __syncthreads();
    cur[t] = atomicAdd(&cursor[t], cnt[t]);
    __syncthreads();
    for (int i = t; i < CHUNK; i += 256) {
        int e = e0 + i;
        if (e >= N_EDGES) break;
        unsigned d = (unsigned)ei[N_EDGES + e];
        int s = ei[e];
        int b = __umulhi(d, MAGIC);
        int pos = atomicAdd(&cur[b], 1);
        srcbuf[pos] = s;
        dstlbuf[pos] = (unsigned short)(d - b * NPB);
    }
}

// ---------------------------------------------------------------------------
// Refine: one block per bucket; LDS counting sort by dst_local; coalesced
// csr_src write; emits rowptr from the local exclusive scan.
// ---------------------------------------------------------------------------
__global__ __launch_bounds__(256) void refine_kernel(const int* __restrict__ srcbuf,
                                                     const unsigned short* __restrict__ dstlbuf,
                                                     const int* __restrict__ base,
                                                     int* __restrict__ csr_src,
                                                     int* __restrict__ rowptr) {
    __shared__ int cnt[NPB + 1];
    __shared__ int cur[NPB + 1];
    __shared__ int tmp[256];
    __shared__ int outb[CAP];
    int t = threadIdx.x, b = blockIdx.x;
    int beg = base[b];
    int end = base[b + 1];

    for (int i = t; i < NPB + 1; i += 256) cnt[i] = 0;
    __syncthreads();
    for (int i = beg + t; i < end; i += 256)
        atomicAdd(&cnt[dstlbuf[i]], 1);
    __syncthreads();

    // exclusive scan over NPB entries (2 elems/thread)
    int i0 = 2 * t, i1 = 2 * t + 1;
    int v0 = (i0 < NPB) ? cnt[i0] : 0;
    int v1 = (i1 < NPB) ? cnt[i1] : 0;
    int s = v0 + v1;
    tmp[t] = s;
    __syncthreads();
    for (int off = 1; off < 256; off <<= 1) {
        int a = (t >= off) ? tmp[t - off] : 0;
        __syncthreads();
        tmp[t] += a;
        __syncthreads();
    }
    int excl = tmp[t] - s;
    if (i0 < NPB) cur[i0] = excl;
    if (i1 < NPB) cur[i1] = excl + v0;
    {
        int g0 = b * NPB + i0;
        if (i0 < NPB && g0 < N_NODES) rowptr[g0] = beg + excl;
        int g1 = b * NPB + i1;
        if (i1 < NPB && g1 < N_NODES) rowptr[g1] = beg + excl + v0;
    }
    if (b == NBUCK - 1 && t == 0) rowptr[N_NODES] = N_EDGES;
    __syncthreads();

    for (int i = beg + t; i < end; i += 256) {
        int dl = dstlbuf[i];
        int pos = atomicAdd(&cur[dl], 1);
        if (pos < CAP) outb[pos] = srcbuf[i];
    }
    __syncthreads();

    int nb = end - beg; if (nb > CAP) nb = CAP;
    for (int i = t; i < nb; i += 256) csr_src[beg + i] = outb[i];
}

// ---------------------------------------------------------------------------
// bf16 gather aggregation: out[i] = feat[i] + sum_{s in nbrs(i)} feat[s]
// 8 lanes per node (16B/lane), 32 nodes per 256-thread block.
// 4-deep software pipeline: 4 independent 16B feature loads in flight/lane;
// accumulation order strictly sequential (bit-identical to 1-deep version).
// ---------------------------------------------------------------------------
__global__ __launch_bounds__(256) void gather_kernel(const unsigned short* __restrict__ feat,
                                                     const int* __restrict__ rowptr,
                                                     const int* __restrict__ csr_src,
                                                     unsigned short* __restrict__ out) {
    int t = threadIdx.x;
    int node = blockIdx.x * 32 + (t >> 3);
    int q = t & 7;
    if (node >= N_NODES) return;
    const u16x8* f8 = (const u16x8*)feat;
    u16x8 sv = f8[(long long)node * 8 + q];
    float acc[8];
    #pragma unroll
    for (int j = 0; j < 8; ++j) acc[j] = bf2f(sv[j]);
    int beg = rowptr[node], end = rowptr[node + 1];
    int k = beg;
    for (; k + 4 <= end; k += 4) {
        int s0 = csr_src[k], s1 = csr_src[k + 1];
        int s2 = csr_src[k + 2], s3 = csr_src[k + 3];
        u16x8 v0 = f8[(long long)s0 * 8 + q];
        u16x8 v1 = f8[(long long)s1 * 8 + q];
        u16x8 v2 = f8[(long long)s2 * 8 + q];
        u16x8 v3 = f8[(long long)s3 * 8 + q];
        #pragma unroll
        for (int j = 0; j < 8; ++j) acc[j] += bf2f(v0[j]);
        #pragma unroll
        for (int j = 0; j < 8; ++j) acc[j] += bf2f(v1[j]);
        #pragma unroll
        for (int j = 0; j < 8; ++j) acc[j] += bf2f(v2[j]);
        #pragma unroll
        for (int j = 0; j < 8; ++j) acc[j] += bf2f(v3[j]);
    }
    for (; k < end; ++k) {
        int sc = csr_src[k];
        u16x8 v = f8[(long long)sc * 8 + q];
        #pragma unroll
        for (int j = 0; j < 8; ++j) acc[j] += bf2f(v[j]);
    }
    u16x8 o;
    #pragma unroll
    for (int j = 0; j < 8; ++j) o[j] = f2bf(acc[j]);
    ((u16x8*)out)[(long long)node * 8 + q] = o;
}

// ---------------------------------------------------------------------------
// B-fragment loader: element j = W[(kt*32 + q*8 + j)][col]  (fp32 W -> bf16)
// ---------------------------------------------------------------------------
__device__ __forceinline__ bfx8 load_wfrag(const float* __restrict__ W, int kt, int q, int col) {
    bfx8 f;
    #pragma unroll
    for (int j = 0; j < 8; ++j)
        f[j] = (short)f2bf(W[(kt * 32 + q * 8 + j) * 64 + col]);
    return f;
}

// ---------------------------------------------------------------------------
// MFMA conv1 MLP: h2 = relu(relu(bn1(h0 @ W1a + b1a)) @ W1b + b1b)
// ---------------------------------------------------------------------------
__global__ __launch_bounds__(256) void mlp1_kernel(
    const unsigned short* __restrict__ h0,
    const float* __restrict__ W1a, const float* __restrict__ b1a,
    const float* __restrict__ g1,  const float* __restrict__ be1,
    const float* __restrict__ m1,  const float* __restrict__ v1,
    const float* __restrict__ W1b, const float* __restrict__ b1b,
    unsigned short* __restrict__ h2) {
    __shared__ unsigned short h1t[4][16 * 72];
    __shared__ unsigned short outt[4][16 * 64];

    int t = threadIdx.x;
    int w = t >> 6, lane = t & 63;
    int m = lane & 15, q = lane >> 4;
    int row0 = blockIdx.x * 64 + w * 16;

    bfx8 wa[4][2], wb[4][2];
    #pragma unroll
    for (int nt = 0; nt < 4; ++nt) {
        #pragma unroll
        for (int kt = 0; kt < 2; ++kt) {
            wa[nt][kt] = load_wfrag(W1a, kt, q, nt * 16 + m);
            wb[nt][kt] = load_wfrag(W1b, kt, q, nt * 16 + m);
        }
    }
    float A1[4], B1[4], B2c[4];
    #pragma unroll
    for (int nt = 0; nt < 4; ++nt) {
        int c = nt * 16 + m;
        float s = g1[c] * rsqrtf(v1[c] + BN_EPS);
        A1[nt] = s;
        B1[nt] = b1a[c] * s + (be1[c] - m1[c] * s);
        B2c[nt] = b1b[c];
    }

    int rowA = row0 + m;
    if (rowA > N_NODES - 1) rowA = N_NODES - 1;
    const bfx8* ap = (const bfx8*)(h0 + (long long)rowA * 64);
    bfx8 a0 = ap[q];
    bfx8 a1 = ap[4 + q];
    f32x4 acc[4];
    #pragma unroll
    for (int nt = 0; nt < 4; ++nt) {
        acc[nt] = (f32x4){0.f, 0.f, 0.f, 0.f};
        acc[nt] = __builtin_amdgcn_mfma_f32_16x16x32_bf16(a0, wa[nt][0], acc[nt], 0, 0, 0);
        acc[nt] = __builtin_amdgcn_mfma_f32_16x16x32_bf16(a1, wa[nt][1], acc[nt], 0, 0, 0);
    }
    #pragma unroll
    for (int nt = 0; nt < 4; ++nt)
        #pragma unroll
        for (int r = 0; r < 4; ++r) {
            float v = fmaxf(acc[nt][r] * A1[nt] + B1[nt], 0.f);
            h1t[w][(q * 4 + r) * 72 + nt * 16 + m] = f2bf(v);
        }
    __syncthreads();

    const bfx8* hp = (const bfx8*)&h1t[w][m * 72];
    bfx8 c0 = hp[q];
    bfx8 c1 = hp[4 + q];
    f32x4 acc2[4];
    #pragma unroll
    for (int nt = 0; nt < 4; ++nt) {
        acc2[nt] = (f32x4){0.f, 0.f, 0.f, 0.f};
        acc2[nt] = __builtin_amdgcn_mfma_f32_16x16x32_bf16(c0, wb[nt][0], acc2[nt], 0, 0, 0);
        acc2[nt] = __builtin_amdgcn_mfma_f32_16x16x32_bf16(c1, wb[nt][1], acc2[nt], 0, 0, 0);
    }
    #pragma unroll
    for (int nt = 0; nt < 4; ++nt)
        #pragma unroll
        for (int r = 0; r < 4; ++r) {
            float v = fmaxf(acc2[nt][r] + B2c[nt], 0.f);
            outt[w][(q * 4 + r) * 64 + nt * 16 + m] = f2bf(v);
        }
    __syncthreads();

    #pragma unroll
    for (int i = lane; i < 128; i += 64) {
        int rr = i >> 3, cc = i & 7;
        int rg = row0 + rr;
        if (rg < N_NODES)
            ((float4*)h2)[(long long)rg * 8 + cc] = *(const float4*)&outt[w][rr * 64 + cc * 8];
    }
}

// ---------------------------------------------------------------------------
// MFMA conv2 + pool: h4 = relu(bn2(h3 @ W2 + b2)); xs[batch[row]] += h4
// ---------------------------------------------------------------------------
__global__ __launch_bounds__(256) void mlp2_kernel(
    const unsigned short* __restrict__ h3,
    const float* __restrict__ W2, const float* __restrict__ b2,
    const float* __restrict__ g2, const float* __restrict__ be2,
    const float* __restrict__ m2, const float* __restrict__ v2,
    const int* __restrict__ batch,
    float* __restrict__ xs) {
    __shared__ float pool[64 * 64];
    __shared__ int bts[64];

    int t = threadIdx.x;
    int w = t >> 6, lane = t & 63;
    int m = lane & 15, q = lane >> 4;
    int row0b = blockIdx.x * 64;
    int row0 = row0b + w * 16;

    bfx8 wf[4][2];
    #pragma unroll
    for (int nt = 0; nt < 4; ++nt)
        #pragma unroll
        for (int kt = 0; kt < 2; ++kt)
            wf[nt][kt] = load_wfrag(W2, kt, q, nt * 16 + m);
    float A[4], Bc[4];
    #pragma unroll
    for (int nt = 0; nt < 4; ++nt) {
        int c = nt * 16 + m;
        float s = g2[c] * rsqrtf(v2[c] + BN_EPS);
        A[nt] = s;
        Bc[nt] = b2[c] * s + (be2[c] - m2[c] * s);
    }
    if (t < 64) {
        int rg = row0b + t;
        bts[t] = (rg < N_NODES) ? batch[rg] : -1;
    }

    int rowA = row0 + m;
    if (rowA > N_NODES - 1) rowA = N_NODES - 1;
    const bfx8* ap = (const bfx8*)(h3 + (long long)rowA * 64);
    bfx8 a0 = ap[q];
    bfx8 a1 = ap[4 + q];
    f32x4 acc[4];
    #pragma unroll
    for (int nt = 0; nt < 4; ++nt) {
        acc[nt] = (f32x4){0.f, 0.f, 0.f, 0.f};
        acc[nt] = __builtin_amdgcn_mfma_f32_16x16x32_bf16(a0, wf[nt][0], acc[nt], 0, 0, 0);
        acc[nt] = __builtin_amdgcn_mfma_f32_16x16x32_bf16(a1, wf[nt][1], acc[nt], 0, 0, 0);
    }
    #pragma unroll
    for (int nt = 0; nt < 4; ++nt)
        #pragma unroll
        for (int r = 0; r < 4; ++r) {
            float v = fmaxf(acc[nt][r] * A[nt] + Bc[nt], 0.f);
            pool[(w * 16 + q * 4 + r) * 64 + nt * 16 + m] = v;
        }
    __syncthreads();

    int col = t & 63;
    int r0 = (t >> 6) * 16;
    int cb = bts[r0];
    float cur = 0.f;
    #pragma unroll
    for (int r = 0; r < 16; ++r) {
        int b = bts[r0 + r];
        if (b != cb) {
            if (cb >= 0) unsafeAtomicAdd(&xs[cb * 64 + col], cur);
            cb = b;
            cur = 0.f;
        }
        cur += pool[(r0 + r) * 64 + col];
    }
    if (cb >= 0) unsafeAtomicAdd(&xs[cb * 64 + col], cur);
}

// ---------------------------------------------------------------------------
// Head: x_topo = relu(topo @ Wt + bt); out = [x_struct, x_topo] @ Wc + bc
// ---------------------------------------------------------------------------
__global__ __launch_bounds__(64) void head_kernel(
    const float* __restrict__ xs, const float* __restrict__ topo,
    const float* __restrict__ Wt, const float* __restrict__ bt,
    const float* __restrict__ Wc, const float* __restrict__ bc,
    float* __restrict__ out) {
    __shared__ float trow[64];
    __shared__ float comb[128];
    int b = blockIdx.x;
    int h = threadIdx.x;
    trow[h] = topo[b * 64 + h];
    __syncthreads();
    float acc = bt[h];
    #pragma unroll
    for (int k = 0; k < 64; ++k) acc += trow[k] * Wt[k * 64 + h];
    comb[h] = xs[b * 64 + h];
    comb[64 + h] = fmaxf(acc, 0.f);
    __syncthreads();
    if (h < NCLASS) {
        float o = bc[h];
        #pragma unroll
        for (int k = 0; k < 128; ++k) o += comb[k] * Wc[k * NCLASS + h];
        out[b * NCLASS + h] = o;
    }
}

// ---------------------------------------------------------------------------
extern "C" void kernel_launch(void* const* d_in, const int* in_sizes, int n_in,
                              void* d_out, int out_size, void* d_ws, size_t ws_size,
                              hipStream_t stream) {
    const float* x     = (const float*)d_in[0];
    const int*   ei    = (const int*)d_in[1];
    const int*   batch = (const int*)d_in[2];
    const float* topo  = (const float*)d_in[3];
    const float* W1a   = (const float*)d_in[4];
    const float* b1a   = (const float*)d_in[5];
    const float* g1    = (const float*)d_in[6];
    const float* be1   = (const float*)d_in[7];
    const float* m1    = (const float*)d_in[8];
    const float* v1    = (const float*)d_in[9];
    const float* W1b   = (const float*)d_in[10];
    const float* b1b   = (const float*)d_in[11];
    const float* W2    = (const float*)d_in[12];
    const float* b2    = (const float*)d_in[13];
    const float* g2    = (const float*)d_in[14];
    const float* be2   = (const float*)d_in[15];
    const float* m2    = (const float*)d_in[16];
    const float* v2    = (const float*)d_in[17];
    const float* Wt    = (const float*)d_in[18];
    const float* bt    = (const float*)d_in[19];
    const float* Wc    = (const float*)d_in[20];
    const float* bc    = (const float*)d_in[21];
    float* out = (float*)d_out;

    // Workspace layout (16B-aligned chunks)
    char* p = (char*)d_ws;
    unsigned short* xbf  = (unsigned short*)p; p += (size_t)N_NODES * DIM * 2;  // 12.8 MB
    unsigned short* bufA = (unsigned short*)p; p += (size_t)N_NODES * DIM * 2;  // 12.8 MB
    unsigned short* bufB = (unsigned short*)p; p += (size_t)N_NODES * DIM * 2;  // 12.8 MB
    float* xs      = (float*)p; p += (size_t)BGRAPHS * DIM * 4;                 // 256 KB
    int*   rowptr  = (int*)p;   p += (size_t)(N_NODES + 16) * 4;                // 400 KB
    int*   gpart   = (int*)p;   p += (size_t)NBLK_P * NBUCK * 4;                // 150 KB
    int*   base    = (int*)p;   p += 1040;                                      // 257 ints (16B-aligned slot)
    int*   cursor  = (int*)p;   p += 1024;                                      // 256 ints
    int*   srcbuf  = (int*)p;   p += (size_t)N_EDGES * 4;                       // 4.8 MB
    unsigned short* dstlbuf = (unsigned short*)p; p += (size_t)N_EDGES * 2;     // 2.4 MB
    int*   csr_src = (int*)p;                                                   // 4.8 MB

    // 1) convert + per-chunk bucket histogram (independent work, one launch)
    convhist_kernel<<<NBLK_P + NB_C, 256, 0, stream>>>(x, xbf, xs, ei, gpart);
    // 2) bucket totals -> exclusive scan -> base/cursor
    scanB_kernel<<<1, 256, 0, stream>>>(gpart, base, cursor);
    // 3) partition edges into bucket regions (chunk reservation, arbitrary order)
    part_kernel<<<NBLK_P, 256, 0, stream>>>(ei, cursor, srcbuf, dstlbuf);
    // 4) per-bucket counting sort -> csr_src + rowptr
    refine_kernel<<<NBUCK, 256, 0, stream>>>(srcbuf, dstlbuf, base, csr_src, rowptr);
    // 5) agg1: bufA = xbf + scatter(xbf)
    gather_kernel<<<(N_NODES + 31) / 32, 256, 0, stream>>>(xbf, rowptr, csr_src, bufA);
    // 6) conv1 MLP (MFMA): bufB = h2 (bf16)
    mlp1_kernel<<<(N_NODES + 63) / 64, 256, 0, stream>>>(
        bufA, W1a, b1a, g1, be1, m1, v1, W1b, b1b, bufB);
    // 7) agg2: bufA = h2 + scatter(h2)
    gather_kernel<<<(N_NODES + 31) / 32, 256, 0, stream>>>(bufB, rowptr, csr_src, bufA);
    // 8) conv2 + pool (MFMA)
    mlp2_kernel<<<(N_NODES + 63) / 64, 256, 0, stream>>>(
        bufA, W2, b2, g2, be2, m2, v2, batch, xs);
    // 9) head
    head_kernel<<<BGRAPHS, 64, 0, stream>>>(xs, topo, Wt, bt, Wc, bc, out);
}